// Round 1
// baseline (327.154 us; speedup 1.0000x reference)
//
#include <hip/hip_runtime.h>
#include <cstdint>
#include <cstddef>

typedef unsigned short u16t;
typedef __bf16 bf16x8_t __attribute__((ext_vector_type(8)));
typedef float f32x4_t __attribute__((ext_vector_type(4)));

#define MFMA_BF16 __builtin_amdgcn_mfma_f32_16x16x32_bf16

__device__ __forceinline__ u16t f2bf(float f) {
    uint32_t u = __builtin_bit_cast(uint32_t, f);
    u += 0x7fffu + ((u >> 16) & 1u);   // RNE
    return (u16t)(u >> 16);
}

__device__ __forceinline__ bf16x8_t ld_frag(const u16t* p) {
    return __builtin_bit_cast(bf16x8_t, *(const uint4*)p);
}

// ---------------- cast f32 -> bf16, 4 elems/thread ----------------
__global__ void cast_bf16_kernel(const float* __restrict__ src, u16t* __restrict__ dst, int n4) {
    int i = blockIdx.x * blockDim.x + threadIdx.x;
    if (i >= n4) return;
    float4 v = ((const float4*)src)[i];
    uint2 o;
    o.x = (uint32_t)f2bf(v.x) | ((uint32_t)f2bf(v.y) << 16);
    o.y = (uint32_t)f2bf(v.z) | ((uint32_t)f2bf(v.w) << 16);
    ((uint2*)dst)[i] = o;
}

// ---------------- transpose + cast: W[K][N] f32 -> Wt[N][K] bf16 ----------------
__global__ void transpose_cast_kernel(const float* __restrict__ W, u16t* __restrict__ Wt,
                                      int K, int N) {
    __shared__ float tile[32][33];
    int n0 = blockIdx.x * 32, k0 = blockIdx.y * 32;
    int tx = threadIdx.x, ty = threadIdx.y;
    for (int i = ty; i < 32; i += 8)
        tile[i][tx] = W[(size_t)(k0 + i) * N + n0 + tx];
    __syncthreads();
    for (int i = ty; i < 32; i += 8)
        Wt[(size_t)(n0 + i) * K + k0 + tx] = f2bf(tile[tx][i]);
}

// ---------------- GEMM: C = A[M][K]bf16 @ Bt[N][K]^T, tile 128x64, 256 thr ----------------
// mode 0: bf16 head-split store out[(h*4096+row)*128+d] * oscale  (Q/K)
// mode 2: bf16 transposed store out[(h*128+d)*4096+row]           (V^T)
// mode 3: f32 store out[row*1024+c] + bias[c]                     (final)
__global__ __launch_bounds__(256) void gemm_bf16_kernel(
    const u16t* __restrict__ A, const u16t* __restrict__ Bt,
    int K, void* __restrict__ outp, const float* __restrict__ bias,
    int mode, float oscale)
{
    __shared__ __align__(16) u16t As[128 * 64];
    __shared__ __align__(16) u16t Bs[64 * 64];
    const int bm = blockIdx.y * 128, bn = blockIdx.x * 64;
    const int tid = threadIdx.x;
    const int wave = tid >> 6, lane = tid & 63;
    const int wm = wave & 1, wn = wave >> 1;
    const int quad = lane >> 4, l16 = lane & 15;

    f32x4_t acc[4][2];
#pragma unroll
    for (int i = 0; i < 4; ++i)
#pragma unroll
        for (int j = 0; j < 2; ++j) acc[i][j] = (f32x4_t){0.f, 0.f, 0.f, 0.f};

    for (int kc = 0; kc < K; kc += 64) {
        __syncthreads();
#pragma unroll
        for (int it = 0; it < 4; ++it) {          // A tile 128x64, XOR-swizzled chunks
            int r = (tid >> 3) + it * 32;
            int c8 = tid & 7;
            uint4 va = *(const uint4*)&A[(size_t)(bm + r) * K + kc + c8 * 8];
            *(uint4*)&As[r * 64 + ((c8 ^ (r & 7)) * 8)] = va;
        }
#pragma unroll
        for (int it = 0; it < 2; ++it) {          // B tile 64x64
            int r = (tid >> 3) + it * 32;
            int c8 = tid & 7;
            uint4 vb = *(const uint4*)&Bt[(size_t)(bn + r) * K + kc + c8 * 8];
            *(uint4*)&Bs[r * 64 + ((c8 ^ (r & 7)) * 8)] = vb;
        }
        __syncthreads();
#pragma unroll
        for (int ks = 0; ks < 2; ++ks) {
            bf16x8_t af[4], bfv[2];
#pragma unroll
            for (int i = 0; i < 4; ++i) {
                int r = wm * 64 + i * 16 + l16;
                af[i] = ld_frag(&As[r * 64 + (((ks * 4 + quad) ^ (r & 7)) * 8)]);
            }
#pragma unroll
            for (int j = 0; j < 2; ++j) {
                int r = wn * 32 + j * 16 + l16;
                bfv[j] = ld_frag(&Bs[r * 64 + (((ks * 4 + quad) ^ (r & 7)) * 8)]);
            }
#pragma unroll
            for (int i = 0; i < 4; ++i)
#pragma unroll
                for (int j = 0; j < 2; ++j)
                    acc[i][j] = MFMA_BF16(af[i], bfv[j], acc[i][j], 0, 0, 0);
        }
    }

    if (mode == 3) {
        float* out = (float*)outp;
#pragma unroll
        for (int j = 0; j < 2; ++j) {
            int c = bn + wn * 32 + j * 16 + l16;
            float b = bias[c];
#pragma unroll
            for (int i = 0; i < 4; ++i) {
                int rb = bm + wm * 64 + i * 16 + quad * 4;
#pragma unroll
                for (int r = 0; r < 4; ++r)
                    out[(size_t)(rb + r) * 1024 + c] = acc[i][j][r] + b;
            }
        }
    } else if (mode == 2) {
        u16t* out = (u16t*)outp;
#pragma unroll
        for (int i = 0; i < 4; ++i)
#pragma unroll
            for (int j = 0; j < 2; ++j) {
                int rb = bm + wm * 64 + i * 16 + quad * 4;
                int c = bn + wn * 32 + j * 16 + l16;
                int h = c >> 7, d = c & 127;
                uint2 pk;
                pk.x = (uint32_t)f2bf(acc[i][j][0]) | ((uint32_t)f2bf(acc[i][j][1]) << 16);
                pk.y = (uint32_t)f2bf(acc[i][j][2]) | ((uint32_t)f2bf(acc[i][j][3]) << 16);
                *(uint2*)&out[((size_t)h * 128 + d) * 4096 + rb] = pk;  // rb % 4 == 0
            }
    } else {
        u16t* out = (u16t*)outp;
#pragma unroll
        for (int i = 0; i < 4; ++i)
#pragma unroll
            for (int j = 0; j < 2; ++j) {
                int rb = bm + wm * 64 + i * 16 + quad * 4;
                int c = bn + wn * 32 + j * 16 + l16;
                int h = c >> 7, d = c & 127;
#pragma unroll
                for (int r = 0; r < 4; ++r)
                    out[((size_t)h * 4096 + rb + r) * 128 + d] = f2bf(acc[i][j][r] * oscale);
            }
    }
}

// ---------------- flash attention: BM=64 q rows, BN=128 keys/iter, 4 waves ----------------
// Qh pre-scaled by tau*SCALE*log2(e): S from MFMA is already in log2 units.
__global__ __launch_bounds__(256) void flash_kernel(
    const u16t* __restrict__ Qh, const u16t* __restrict__ Kh,
    const u16t* __restrict__ Vtg, u16t* __restrict__ Oh)
{
    const int h = blockIdx.x;            // fastest index -> heads spread across XCDs
    const int q0 = blockIdx.y * 64;
    const int tid = threadIdx.x;
    const int wave = tid >> 6, lane = tid & 63;
    const int quad = lane >> 4, l16 = lane & 15;

    __shared__ __align__(16) u16t KVs[128 * 128];  // K tile, then V^T tile (phase-shared)
    __shared__ __align__(16) u16t QPs[64 * 128];   // Q tile, then per-wave P scratch

    {   // stage Q (64x128), XOR-swizzled 16B chunks
        const u16t* Qg = Qh + ((size_t)h * 4096 + q0) * 128;
#pragma unroll
        for (int it = 0; it < 4; ++it) {
            int r = (tid >> 4) + it * 16;
            int c8 = tid & 15;
            uint4 v = *(const uint4*)&Qg[r * 128 + c8 * 8];
            *(uint4*)&QPs[r * 128 + ((c8 ^ (r & 15)) * 8)] = v;
        }
    }
    __syncthreads();
    bf16x8_t qf[4];                      // this wave's 16 q-rows, A-fragments (kept in regs)
    {
        int r = wave * 16 + l16;
#pragma unroll
        for (int ks = 0; ks < 4; ++ks)
            qf[ks] = ld_frag(&QPs[r * 128 + (((ks * 4 + quad) ^ (r & 15)) * 8)]);
    }

    f32x4_t O[8];
#pragma unroll
    for (int dt = 0; dt < 8; ++dt) O[dt] = (f32x4_t){0.f, 0.f, 0.f, 0.f};
    float m_i[4] = {-1e30f, -1e30f, -1e30f, -1e30f};
    float l_i[4] = {0.f, 0.f, 0.f, 0.f};

    const u16t* Kg = Kh + (size_t)h * 4096 * 128;
    const u16t* Vg = Vtg + (size_t)h * 128 * 4096;

    for (int kb = 0; kb < 32; ++kb) {
        const int j0 = kb * 128;
        __syncthreads();                 // prev PV reads of KVs done
#pragma unroll
        for (int it = 0; it < 8; ++it) { // stage K tile 128 keys x 128 d
            int r = (tid >> 4) + it * 16;
            int c8 = tid & 15;
            uint4 v = *(const uint4*)&Kg[(size_t)(j0 + r) * 128 + c8 * 8];
            *(uint4*)&KVs[r * 128 + ((c8 ^ (r & 15)) * 8)] = v;
        }
        __syncthreads();

        f32x4_t S[8];
#pragma unroll
        for (int jt = 0; jt < 8; ++jt) S[jt] = (f32x4_t){0.f, 0.f, 0.f, 0.f};
#pragma unroll
        for (int jt = 0; jt < 8; ++jt) {
            int rk = jt * 16 + l16;
#pragma unroll
            for (int ks = 0; ks < 4; ++ks) {
                bf16x8_t kf = ld_frag(&KVs[rk * 128 + (((ks * 4 + quad) ^ (rk & 15)) * 8)]);
                S[jt] = MFMA_BF16(qf[ks], kf, S[jt], 0, 0, 0);
            }
        }

        // ---- online softmax (log2 domain); row = quad*4 + r, cols across l16 & jt ----
        float alpha[4];
#pragma unroll
        for (int r = 0; r < 4; ++r) {
            float mx = S[0][r];
#pragma unroll
            for (int jt = 1; jt < 8; ++jt) mx = fmaxf(mx, S[jt][r]);
            mx = fmaxf(mx, __shfl_xor(mx, 1, 64));
            mx = fmaxf(mx, __shfl_xor(mx, 2, 64));
            mx = fmaxf(mx, __shfl_xor(mx, 4, 64));
            mx = fmaxf(mx, __shfl_xor(mx, 8, 64));
            float mnew = fmaxf(m_i[r], mx);
            alpha[r] = __builtin_amdgcn_exp2f(m_i[r] - mnew);
            m_i[r] = mnew;
        }
#pragma unroll
        for (int jt = 0; jt < 8; ++jt)
#pragma unroll
            for (int r = 0; r < 4; ++r)
                S[jt][r] = __builtin_amdgcn_exp2f(S[jt][r] - m_i[r]);
#pragma unroll
        for (int r = 0; r < 4; ++r) {
            float s = 0.f;
#pragma unroll
            for (int jt = 0; jt < 8; ++jt) s += S[jt][r];
            s += __shfl_xor(s, 1, 64);
            s += __shfl_xor(s, 2, 64);
            s += __shfl_xor(s, 4, 64);
            s += __shfl_xor(s, 8, 64);
            l_i[r] = l_i[r] * alpha[r] + s;
        }
#pragma unroll
        for (int dt = 0; dt < 8; ++dt)
#pragma unroll
            for (int r = 0; r < 4; ++r) O[dt][r] *= alpha[r];

        // write P (bf16) into this wave's own 16 rows of QPs (C-layout -> A-layout)
#pragma unroll
        for (int jt = 0; jt < 8; ++jt)
#pragma unroll
            for (int r = 0; r < 4; ++r) {
                int row = wave * 16 + quad * 4 + r;
                int j = jt * 16 + l16;
                QPs[row * 128 + (((j >> 3) ^ (row & 15)) * 8) + (j & 7)] = f2bf(S[jt][r]);
            }
        __syncthreads();                 // all waves done reading K tile
#pragma unroll
        for (int it = 0; it < 8; ++it) { // stage V^T tile: rows = d, cols = key j
            int r = (tid >> 4) + it * 16;
            int c8 = tid & 15;
            uint4 v = *(const uint4*)&Vg[(size_t)r * 4096 + j0 + c8 * 8];
            *(uint4*)&KVs[r * 128 + ((c8 ^ (r & 15)) * 8)] = v;
        }
        __syncthreads();
        {
            int rp = wave * 16 + l16;
#pragma unroll
            for (int ks = 0; ks < 4; ++ks) {
                bf16x8_t pf = ld_frag(&QPs[rp * 128 + (((ks * 4 + quad) ^ (rp & 15)) * 8)]);
#pragma unroll
                for (int dt = 0; dt < 8; ++dt) {
                    int rv = dt * 16 + l16;
                    bf16x8_t vf = ld_frag(&KVs[rv * 128 + (((ks * 4 + quad) ^ (rv & 15)) * 8)]);
                    O[dt] = MFMA_BF16(pf, vf, O[dt], 0, 0, 0);
                }
            }
        }
    }

    // epilogue: O /= l, store bf16 to Oh[i][h*128+d] (merged-head layout)
#pragma unroll
    for (int r = 0; r < 4; ++r) {
        float inv = 1.f / l_i[r];
        size_t i = (size_t)(q0 + wave * 16 + quad * 4 + r);
#pragma unroll
        for (int dt = 0; dt < 8; ++dt)
            Oh[i * 1024 + h * 128 + dt * 16 + l16] = f2bf(O[dt][r] * inv);
    }
}

// =====================================================================
extern "C" void kernel_launch(void* const* d_in, const int* in_sizes, int n_in,
                              void* d_out, int out_size, void* d_ws, size_t ws_size,
                              hipStream_t stream)
{
    (void)in_sizes; (void)n_in; (void)out_size; (void)ws_size;
    const float* x    = (const float*)d_in[0];   // (2,2048,1024)
    const float* ctx  = (const float*)d_in[1];   // (2,2048,768)
    const float* Wq   = (const float*)d_in[2];   // (1024,1024)
    const float* Wk   = (const float*)d_in[3];   // (768,1024)
    const float* Wv   = (const float*)d_in[4];   // (768,1024)
    const float* Wout = (const float*)d_in[5];   // (1024,1024)
    const float* bout = (const float*)d_in[6];   // (1024,)
    float* out = (float*)d_out;                  // (2,2048,1024) f32

    u16t* ws = (u16t*)d_ws;                      // ~47 MB of bf16 scratch
    u16t* x_bf   = ws;                           // 4194304
    u16t* ctx_bf = x_bf + 4194304;               // 3145728
    u16t* Wqt    = ctx_bf + 3145728;             // 1048576  [N=1024][K=1024]
    u16t* Wkt    = Wqt + 1048576;                // 786432   [1024][768]
    u16t* Wvt    = Wkt + 786432;                 // 786432
    u16t* Woutt  = Wvt + 786432;                 // 1048576
    u16t* Qh     = Woutt + 1048576;              // 4194304  [8][4096][128]
    u16t* Kh     = Qh + 4194304;                 // 4194304
    u16t* Vt     = Kh + 4194304;                 // 4194304  [8][128][4096]
    u16t* Oh     = x_bf;                         // reuse: x_bf dead after Q projection

    // tau * dim^-0.5 * log2(e), folded into Q so flash uses raw exp2
    constexpr float QSCALE = 1.5f * 0.08838834764831845f * 1.4426950408889634f;

    cast_bf16_kernel<<<4096, 256, 0, stream>>>(x, x_bf, 1048576);
    cast_bf16_kernel<<<3072, 256, 0, stream>>>(ctx, ctx_bf, 786432);
    transpose_cast_kernel<<<dim3(32, 32), dim3(32, 8), 0, stream>>>(Wq, Wqt, 1024, 1024);
    transpose_cast_kernel<<<dim3(32, 24), dim3(32, 8), 0, stream>>>(Wk, Wkt, 768, 1024);
    transpose_cast_kernel<<<dim3(32, 24), dim3(32, 8), 0, stream>>>(Wv, Wvt, 768, 1024);
    transpose_cast_kernel<<<dim3(32, 32), dim3(32, 8), 0, stream>>>(Wout, Woutt, 1024, 1024);

    gemm_bf16_kernel<<<dim3(16, 32), 256, 0, stream>>>(x_bf,   Wqt, 1024, Qh, nullptr, 0, QSCALE);
    gemm_bf16_kernel<<<dim3(16, 32), 256, 0, stream>>>(ctx_bf, Wkt,  768, Kh, nullptr, 0, 1.0f);
    gemm_bf16_kernel<<<dim3(16, 32), 256, 0, stream>>>(ctx_bf, Wvt,  768, Vt, nullptr, 2, 1.0f);

    flash_kernel<<<dim3(8, 64), 256, 0, stream>>>(Qh, Kh, Vt, Oh);

    gemm_bf16_kernel<<<dim3(16, 32), 256, 0, stream>>>(Oh, Woutt, 1024, out, bout, 3, 1.0f);
}